// Round 2
// baseline (10418.201 us; speedup 1.0000x reference)
//
#include <hip/hip_runtime.h>
#include <hip/hip_bf16.h>

#define SEQ 2048
#define HIDDEN 4096
#define NHEAD 32
#define NKVH 8
#define HDIM 128
#define SCALE 0.08838834764831845f

// C[m][n] = sum_k A[m][k] * B[n][k]; A: MxK fp32 (row-major), B: NxK fp32 (row-major)
// M,N multiples of 64; K multiple of 16.
__global__ __launch_bounds__(256) void gemm_nt(const float* __restrict__ A,
                                               const float* __restrict__ B,
                                               float* __restrict__ C,
                                               int M, int N, int K) {
    const int BK = 16;
    __shared__ float As[64][BK + 4];
    __shared__ float Bs[64][BK + 4];
    int tid = threadIdx.x;
    int tx = tid & 15, ty = tid >> 4;
    int m0 = blockIdx.y * 64, n0 = blockIdx.x * 64;
    float acc[4][4] = {};
    for (int k0 = 0; k0 < K; k0 += BK) {
        // stage tiles: 64x16 fp32 each; thread loads 4 contiguous floats (16B)
        int flat = tid * 4;
        int r = flat >> 4, c = flat & 15;
        float4 av = *(const float4*)(A + (size_t)(m0 + r) * K + k0 + c);
        As[r][c]     = av.x;
        As[r][c + 1] = av.y;
        As[r][c + 2] = av.z;
        As[r][c + 3] = av.w;
        float4 bv = *(const float4*)(B + (size_t)(n0 + r) * K + k0 + c);
        Bs[r][c]     = bv.x;
        Bs[r][c + 1] = bv.y;
        Bs[r][c + 2] = bv.z;
        Bs[r][c + 3] = bv.w;
        __syncthreads();
        #pragma unroll
        for (int kk = 0; kk < BK; kk += 4) {
            float4 a4[4], b4[4];
            #pragma unroll
            for (int i = 0; i < 4; ++i) a4[i] = *(const float4*)&As[ty * 4 + i][kk];
            #pragma unroll
            for (int j = 0; j < 4; ++j) b4[j] = *(const float4*)&Bs[tx * 4 + j][kk];
            #pragma unroll
            for (int i = 0; i < 4; ++i)
                #pragma unroll
                for (int j = 0; j < 4; ++j) {
                    acc[i][j] += a4[i].x * b4[j].x;
                    acc[i][j] += a4[i].y * b4[j].y;
                    acc[i][j] += a4[i].z * b4[j].z;
                    acc[i][j] += a4[i].w * b4[j].w;
                }
        }
        __syncthreads();
    }
    #pragma unroll
    for (int i = 0; i < 4; ++i) {
        int row = m0 + ty * 4 + i;
        #pragma unroll
        for (int j = 0; j < 4; ++j) {
            int col = n0 + tx * 4 + j;
            C[(size_t)row * N + col] = acc[i][j];
        }
    }
}

// In-place RoPE on fp32 [SEQ][nh*HDIM]; cos/sin: fp32 [SEQ][HDIM] with
// cos[s][d] == cos[s][d+64], so each thread rotates the (d, d+64) pair.
__global__ __launch_bounds__(256) void rope_kernel(float* __restrict__ x,
                                                   const float* __restrict__ cosb,
                                                   const float* __restrict__ sinb,
                                                   int nh) {
    int idx = blockIdx.x * 256 + threadIdx.x;  // total SEQ*nh*64
    int d = idx & 63;
    int t = idx >> 6;
    int h = t % nh;
    int s = t / nh;
    float cs = cosb[s * HDIM + d];
    float sn = sinb[s * HDIM + d];
    float* p = x + (size_t)s * nh * HDIM + h * HDIM + d;
    float x1 = p[0], x2 = p[64];
    p[0]  = x1 * cs - x2 * sn;
    p[64] = x2 * cs + x1 * sn;
}

// Flash-style causal GQA attention.
// grid (SEQ/4, NHEAD), block 256 (4 waves). Wave w handles q row s0+w of head blockIdx.y.
// q: fp32 [SEQ][NHEAD*HDIM]; k,v: fp32 [SEQ][NKVH*HDIM]; out: fp32 [SEQ][NHEAD*HDIM]
__global__ __launch_bounds__(256) void attn_kernel(const float* __restrict__ q,
                                                   const float* __restrict__ kbuf,
                                                   const float* __restrict__ vbuf,
                                                   float* __restrict__ ao) {
    __shared__ float qs[4][HDIM];
    __shared__ float kt[64][HDIM + 1];   // pad +1: score reads conflict-free
    __shared__ float ps[4][64];
    int h = blockIdx.y;
    int s0 = blockIdx.x * 4;
    int kvh = h >> 2;                     // NHEAD/NKVH = 4
    int tid = threadIdx.x;
    int w = tid >> 6, lane = tid & 63;

    for (int i = tid; i < 4 * HDIM; i += 256) {
        int r = i >> 7, c = i & 127;
        qs[r][c] = q[(size_t)(s0 + r) * (NHEAD * HDIM) + h * HDIM + c];
    }

    int srow = s0 + w;
    float m = -1e30f, l = 0.f, acc0 = 0.f, acc1 = 0.f;
    int ntiles = (s0 + 3) / 64 + 1;       // block-uniform => __syncthreads is uniform

    for (int t = 0; t < ntiles; ++t) {
        __syncthreads();
        // stage K tile 64x128 fp32 (float4 global loads, scalar LDS stores into padded rows)
        for (int i = tid; i < 64 * 32; i += 256) {
            int r = i >> 5, c4 = (i & 31) * 4;
            float4 k4 = *(const float4*)&kbuf[(size_t)(t * 64 + r) * (NKVH * HDIM) + kvh * HDIM + c4];
            kt[r][c4]     = k4.x;
            kt[r][c4 + 1] = k4.y;
            kt[r][c4 + 2] = k4.z;
            kt[r][c4 + 3] = k4.w;
        }
        __syncthreads();

        int kg = t * 64 + lane;
        float sc = -1e30f;
        if (kg <= srow) {
            float ssum = 0.f;
            #pragma unroll
            for (int d = 0; d < HDIM; ++d) ssum += qs[w][d] * kt[lane][d];
            sc = ssum * SCALE;
        }
        // wave max
        float mt = sc;
        #pragma unroll
        for (int off = 32; off > 0; off >>= 1) mt = fmaxf(mt, __shfl_xor(mt, off));
        float m_new = fmaxf(m, mt);
        float alpha = __expf(m - m_new);
        float p = (kg <= srow) ? __expf(sc - m_new) : 0.f;
        float psum = p;
        #pragma unroll
        for (int off = 32; off > 0; off >>= 1) psum += __shfl_xor(psum, off);
        l = l * alpha + psum;
        acc0 *= alpha;
        acc1 *= alpha;
        m = m_new;
        ps[w][lane] = p;
        __syncthreads();
        // PV: lane owns dims (2*lane, 2*lane+1); coalesced float2 loads of V rows
        const float* vrow = vbuf + (size_t)(t * 64) * (NKVH * HDIM) + kvh * HDIM + 2 * lane;
        #pragma unroll 8
        for (int j = 0; j < 64; ++j) {
            float pj = ps[w][j];
            float2 vv = *(const float2*)(vrow + (size_t)j * (NKVH * HDIM));
            acc0 += pj * vv.x;
            acc1 += pj * vv.y;
        }
    }
    float inv = 1.f / l;
    float* op = ao + (size_t)srow * (NHEAD * HDIM) + h * HDIM + 2 * lane;
    op[0] = acc0 * inv;
    op[1] = acc1 * inv;
}

extern "C" void kernel_launch(void* const* d_in, const int* in_sizes, int n_in,
                              void* d_out, int out_size, void* d_ws, size_t ws_size,
                              hipStream_t stream) {
    const float* hidden = (const float*)d_in[0];  // fp32 [1,2048,4096]
    const float* cosb   = (const float*)d_in[1];  // fp32 [1,2048,128]
    const float* sinb   = (const float*)d_in[2];  // fp32 [1,2048,128]
    const float* wq     = (const float*)d_in[3];  // fp32 [4096,4096]
    const float* wk     = (const float*)d_in[4];  // fp32 [1024,4096]
    const float* wv     = (const float*)d_in[5];  // fp32 [1024,4096]
    const float* wo     = (const float*)d_in[6];  // fp32 [4096,4096]
    // d_in[7..9]: k_cache, v_cache, block_ids — scatter/gather is identity on used data; unused.

    // workspace layout (all fp32)
    float* qb = (float*)d_ws;                              // SEQ*NHEAD*HDIM
    float* kb = qb + (size_t)SEQ * NHEAD * HDIM;           // SEQ*NKVH*HDIM
    float* vb = kb + (size_t)SEQ * NKVH * HDIM;            // SEQ*NKVH*HDIM
    float* ao = vb + (size_t)SEQ * NKVH * HDIM;            // SEQ*NHEAD*HDIM

    dim3 blk(256);
    // projections
    gemm_nt<<<dim3((NHEAD * HDIM) / 64, SEQ / 64), blk, 0, stream>>>(hidden, wq, qb, SEQ, NHEAD * HDIM, HIDDEN);
    gemm_nt<<<dim3((NKVH * HDIM) / 64, SEQ / 64), blk, 0, stream>>>(hidden, wk, kb, SEQ, NKVH * HDIM, HIDDEN);
    gemm_nt<<<dim3((NKVH * HDIM) / 64, SEQ / 64), blk, 0, stream>>>(hidden, wv, vb, SEQ, NKVH * HDIM, HIDDEN);
    // RoPE on q and k
    rope_kernel<<<dim3(SEQ * NHEAD * 64 / 256), blk, 0, stream>>>(qb, cosb, sinb, NHEAD);
    rope_kernel<<<dim3(SEQ * NKVH * 64 / 256), blk, 0, stream>>>(kb, cosb, sinb, NKVH);
    // causal GQA attention
    attn_kernel<<<dim3(SEQ / 4, NHEAD), blk, 0, stream>>>(qb, kb, vb, ao);
    // output projection
    gemm_nt<<<dim3(HIDDEN / 64, SEQ / 64), blk, 0, stream>>>(ao, wo, (float*)d_out, SEQ, HIDDEN, NHEAD * HDIM);
}

// Round 3
// 2314.041 us; speedup vs baseline: 4.5022x; 4.5022x over previous
//
#include <hip/hip_runtime.h>
#include <hip/hip_bf16.h>
#include <stdint.h>

#define SEQ 2048
#define HIDDEN 4096
#define NHEAD 32
#define NKVH 8
#define HDIM 128
#define SCALE 0.08838834764831845f

typedef __bf16 bf16x8 __attribute__((ext_vector_type(8)));
typedef float floatx4 __attribute__((ext_vector_type(4)));

__device__ inline float bf2f(unsigned int u16) {
    union { unsigned int i; float f; } x;
    x.i = u16 << 16;
    return x.f;
}
__device__ inline unsigned short f2bf(float f) {
    union { float f; unsigned int u; } x;
    x.f = f;
    unsigned int r = x.u + 0x7FFF + ((x.u >> 16) & 1);   // RNE; inputs are finite/normal
    return (unsigned short)(r >> 16);
}

// fp32 -> bf16 cast, 4 elems/thread
__global__ __launch_bounds__(256) void cast_f32_bf16(const float* __restrict__ s,
                                                     unsigned short* __restrict__ d, int n4) {
    int i = blockIdx.x * 256 + threadIdx.x;
    if (i < n4) {
        float4 v = ((const float4*)s)[i];
        ushort4 o;
        o.x = f2bf(v.x); o.y = f2bf(v.y); o.z = f2bf(v.z); o.w = f2bf(v.w);
        ((ushort4*)d)[i] = o;
    }
}

__device__ inline void storeC(float* p, float v) { *p = v; }
__device__ inline void storeC(unsigned short* p, float v) { *p = f2bf(v); }

// async 16B global->LDS (dst = wave-uniform base + lane*16; layout below matches)
#define GLL16(gp, lp) __builtin_amdgcn_global_load_lds( \
    (const __attribute__((address_space(1))) unsigned int*)(gp), \
    (__attribute__((address_space(3))) unsigned int*)(lp), 16, 0, 0)

// C[m][n] = sum_k A[m][k]*B[n][k]; A: MxK bf16 row-major, B: NxK bf16 row-major.
// 128x128 tile, BK=32, 4 waves in 2x2, each wave 64x64 via 4x4 grid of 16x16x32 MFMA.
template <typename OutT>
__global__ __launch_bounds__(256) void gemm_nt_mfma(const unsigned short* __restrict__ A,
                                                    const unsigned short* __restrict__ B,
                                                    OutT* __restrict__ C,
                                                    int M, int N, int K) {
    __shared__ unsigned short As[128 * 32];   // row-major 128 rows x 32 bf16 (64B rows)
    __shared__ unsigned short Bs[128 * 32];
    const int tid = threadIdx.x;
    const int lane = tid & 63;
    const int w = tid >> 6;
    const int m0 = blockIdx.y * 128, n0 = blockIdx.x * 128;
    const int wr = (w >> 1) * 64, wc = (w & 1) * 64;
    const int srow = tid >> 2;            // staging row 0..63 (+64 on 2nd load)
    const int scol = (tid & 3) * 8;       // staging col (bf16 elems)
    const int quad = lane >> 4, l16 = lane & 15;

    floatx4 acc[4][4] = {};

    for (int k0 = 0; k0 < K; k0 += 32) {
        __syncthreads();   // all frag reads from previous tile done before overwrite
        const unsigned short* gA = A + (size_t)(m0 + srow) * K + k0 + scol;
        const unsigned short* gB = B + (size_t)(n0 + srow) * K + k0 + scol;
        GLL16(gA,                    As + srow * 32 + scol);
        GLL16(gA + (size_t)64 * K,   As + (64 + srow) * 32 + scol);
        GLL16(gB,                    Bs + srow * 32 + scol);
        GLL16(gB + (size_t)64 * K,   Bs + (64 + srow) * 32 + scol);
        __syncthreads();   // barrier drains vmcnt -> LDS tiles valid

        bf16x8 af[4], bg[4];
        #pragma unroll
        for (int i = 0; i < 4; ++i)
            af[i] = *(const bf16x8*)(As + (wr + i * 16 + l16) * 32 + quad * 8);
        #pragma unroll
        for (int j = 0; j < 4; ++j)
            bg[j] = *(const bf16x8*)(Bs + (wc + j * 16 + l16) * 32 + quad * 8);
        #pragma unroll
        for (int i = 0; i < 4; ++i)
            #pragma unroll
            for (int j = 0; j < 4; ++j)
                acc[i][j] = __builtin_amdgcn_mfma_f32_16x16x32_bf16(af[i], bg[j], acc[i][j], 0, 0, 0);
    }

    // C/D layout: col = lane&15, row = quad*4 + reg   [measured m89/m91]
    #pragma unroll
    for (int i = 0; i < 4; ++i) {
        #pragma unroll
        for (int j = 0; j < 4; ++j) {
            int col = n0 + wc + j * 16 + l16;
            int rowb = m0 + wr + i * 16 + quad * 4;
            #pragma unroll
            for (int r = 0; r < 4; ++r)
                storeC(&C[(size_t)(rowb + r) * N + col], acc[i][j][r]);
        }
    }
}

// In-place RoPE on bf16 [SEQ][nh*HDIM]; cos/sin fp32 [SEQ][HDIM], cos[s][d]==cos[s][d+64].
__global__ __launch_bounds__(256) void rope_bf16(unsigned short* __restrict__ x,
                                                 const float* __restrict__ cosb,
                                                 const float* __restrict__ sinb,
                                                 int nh) {
    int idx = blockIdx.x * 256 + threadIdx.x;   // SEQ*nh*64 threads
    int d = idx & 63;
    int t = idx >> 6;
    int h = t % nh;
    int s = t / nh;
    float cs = cosb[s * HDIM + d];
    float sn = sinb[s * HDIM + d];
    unsigned short* p = x + (size_t)s * nh * HDIM + h * HDIM + d;
    float x1 = bf2f(p[0]), x2 = bf2f(p[64]);
    p[0]  = f2bf(x1 * cs - x2 * sn);
    p[64] = f2bf(x2 * cs + x1 * sn);
}

// Flash-style causal GQA attention, bf16 q/k/v/out, fp32 accumulate.
// grid (SEQ/4, NHEAD), block 256 (4 waves); wave w owns q-row s0+w of head blockIdx.y.
__global__ __launch_bounds__(256) void attn_kernel(const unsigned short* __restrict__ qg,
                                                   const unsigned short* __restrict__ kgb,
                                                   const unsigned short* __restrict__ vgb,
                                                   unsigned short* __restrict__ ao) {
    __shared__ float qs[4][HDIM];
    __shared__ float kt[64][HDIM + 1];   // pad +1: conflict-free score reads
    __shared__ float ps[4][64];
    int h = blockIdx.y;
    int s0 = blockIdx.x * 4;
    int kvh = h >> 2;                     // NHEAD/NKVH = 4
    int tid = threadIdx.x;
    int w = tid >> 6, lane = tid & 63;

    for (int i = tid; i < 4 * HDIM; i += 256) {
        int r = i >> 7, c = i & 127;
        qs[r][c] = bf2f(qg[(size_t)(s0 + r) * (NHEAD * HDIM) + h * HDIM + c]);
    }

    int srow = s0 + w;
    float m = -1e30f, l = 0.f, acc0 = 0.f, acc1 = 0.f;
    int ntiles = (s0 + 3) / 64 + 1;       // block-uniform

    for (int t = 0; t < ntiles; ++t) {
        __syncthreads();
        // stage K tile 64x128 bf16 -> fp32 LDS (16B global loads)
        for (int i = tid; i < 64 * 16; i += 256) {
            int r = i >> 4, c8 = (i & 15) * 8;
            uint4 u = *(const uint4*)&kgb[(size_t)(t * 64 + r) * (NKVH * HDIM) + kvh * HDIM + c8];
            kt[r][c8 + 0] = bf2f(u.x & 0xffff); kt[r][c8 + 1] = bf2f(u.x >> 16);
            kt[r][c8 + 2] = bf2f(u.y & 0xffff); kt[r][c8 + 3] = bf2f(u.y >> 16);
            kt[r][c8 + 4] = bf2f(u.z & 0xffff); kt[r][c8 + 5] = bf2f(u.z >> 16);
            kt[r][c8 + 6] = bf2f(u.w & 0xffff); kt[r][c8 + 7] = bf2f(u.w >> 16);
        }
        __syncthreads();

        int kg = t * 64 + lane;
        float sc = -1e30f;
        if (kg <= srow) {
            float ssum = 0.f;
            #pragma unroll
            for (int d = 0; d < HDIM; ++d) ssum += qs[w][d] * kt[lane][d];
            sc = ssum * SCALE;
        }
        float mt = sc;
        #pragma unroll
        for (int off = 32; off > 0; off >>= 1) mt = fmaxf(mt, __shfl_xor(mt, off));
        float m_new = fmaxf(m, mt);
        float alpha = __expf(m - m_new);
        float p = (kg <= srow) ? __expf(sc - m_new) : 0.f;
        float psum = p;
        #pragma unroll
        for (int off = 32; off > 0; off >>= 1) psum += __shfl_xor(psum, off);
        l = l * alpha + psum;
        acc0 *= alpha;
        acc1 *= alpha;
        m = m_new;
        ps[w][lane] = p;
        __syncthreads();
        // PV: lane owns dims (2*lane, 2*lane+1); 4B bf16x2 loads, coalesced
        const unsigned short* vrow = vgb + (size_t)(t * 64) * (NKVH * HDIM) + kvh * HDIM + 2 * lane;
        #pragma unroll 8
        for (int j = 0; j < 64; ++j) {
            float pj = ps[w][j];
            unsigned int u = *(const unsigned int*)(vrow + (size_t)j * (NKVH * HDIM));
            acc0 += pj * bf2f(u & 0xffff);
            acc1 += pj * bf2f(u >> 16);
        }
    }
    float inv = 1.f / l;
    unsigned int packed = ((unsigned int)f2bf(acc1 * inv) << 16) | f2bf(acc0 * inv);
    *(unsigned int*)(ao + (size_t)srow * (NHEAD * HDIM) + h * HDIM + 2 * lane) = packed;
}

extern "C" void kernel_launch(void* const* d_in, const int* in_sizes, int n_in,
                              void* d_out, int out_size, void* d_ws, size_t ws_size,
                              hipStream_t stream) {
    const float* hidden = (const float*)d_in[0];  // fp32 [1,2048,4096]
    const float* cosb   = (const float*)d_in[1];  // fp32 [1,2048,128]
    const float* sinb   = (const float*)d_in[2];  // fp32 [1,2048,128]
    const float* wq     = (const float*)d_in[3];  // fp32 [4096,4096]
    const float* wk     = (const float*)d_in[4];  // fp32 [1024,4096]
    const float* wv     = (const float*)d_in[5];  // fp32 [1024,4096]
    const float* wo     = (const float*)d_in[6];  // fp32 [4096,4096]
    // d_in[7..9]: k_cache/v_cache/block_ids — scatter+gather by same ids == identity; unused.

    // bf16 workspace (stream-ordered reuse keeps total at 75.6 MB)
    unsigned short* hb = (unsigned short*)d_ws;              // hidden bf16; later reused as attn out
    unsigned short* wb = hb + (size_t)SEQ * HIDDEN;          // current weight bf16 (max 16.8M elems)
    unsigned short* qb = wb + (size_t)HIDDEN * HIDDEN;       // q bf16
    unsigned short* kb = qb + (size_t)SEQ * NHEAD * HDIM;    // k bf16
    unsigned short* vb = kb + (size_t)SEQ * NKVH * HDIM;     // v bf16
    unsigned short* ao = hb;                                 // attn output overlays hidden

    dim3 blk(256);
    cast_f32_bf16<<<dim3(SEQ * HIDDEN / 1024), blk, 0, stream>>>(hidden, hb, SEQ * HIDDEN / 4);

    // Q projection
    cast_f32_bf16<<<dim3(HIDDEN * HIDDEN / 1024), blk, 0, stream>>>(wq, wb, HIDDEN * HIDDEN / 4);
    gemm_nt_mfma<unsigned short><<<dim3((NHEAD * HDIM) / 128, SEQ / 128), blk, 0, stream>>>(
        hb, wb, qb, SEQ, NHEAD * HDIM, HIDDEN);
    // K projection
    cast_f32_bf16<<<dim3(NKVH * HDIM * HIDDEN / 1024), blk, 0, stream>>>(wk, wb, NKVH * HDIM * HIDDEN / 4);
    gemm_nt_mfma<unsigned short><<<dim3((NKVH * HDIM) / 128, SEQ / 128), blk, 0, stream>>>(
        hb, wb, kb, SEQ, NKVH * HDIM, HIDDEN);
    // V projection
    cast_f32_bf16<<<dim3(NKVH * HDIM * HIDDEN / 1024), blk, 0, stream>>>(wv, wb, NKVH * HDIM * HIDDEN / 4);
    gemm_nt_mfma<unsigned short><<<dim3((NKVH * HDIM) / 128, SEQ / 128), blk, 0, stream>>>(
        hb, wb, vb, SEQ, NKVH * HDIM, HIDDEN);

    // RoPE on q and k (in-place, bf16)
    rope_bf16<<<dim3(SEQ * NHEAD * 64 / 256), blk, 0, stream>>>(qb, cosb, sinb, NHEAD);
    rope_bf16<<<dim3(SEQ * NKVH * 64 / 256), blk, 0, stream>>>(kb, cosb, sinb, NKVH);

    // causal GQA attention (writes ao = hb region; hidden no longer needed)
    attn_kernel<<<dim3(SEQ / 4, NHEAD), blk, 0, stream>>>(qb, kb, vb, ao);

    // output projection (fp32 out)
    cast_f32_bf16<<<dim3(HIDDEN * HIDDEN / 1024), blk, 0, stream>>>(wo, wb, HIDDEN * HIDDEN / 4);
    gemm_nt_mfma<float><<<dim3(HIDDEN / 128, SEQ / 128), blk, 0, stream>>>(
        ao, wb, (float*)d_out, SEQ, HIDDEN, NHEAD * HDIM);
}

// Round 4
// 881.116 us; speedup vs baseline: 11.8239x; 2.6263x over previous
//
#include <hip/hip_runtime.h>
#include <hip/hip_bf16.h>
#include <stdint.h>

#define SEQ 2048
#define HIDDEN 4096
#define NHEAD 32
#define NKVH 8
#define HDIM 128
#define NQT (SEQ / 64)
#define SCALE 0.08838834764831845f

typedef __bf16 bf16x8 __attribute__((ext_vector_type(8)));
typedef float floatx4 __attribute__((ext_vector_type(4)));

__device__ inline float bf2f(unsigned int u16) {
    union { unsigned int i; float f; } x;
    x.i = u16 << 16;
    return x.f;
}
__device__ inline unsigned short f2bf(float f) {
    union { float f; unsigned int u; } x;
    x.f = f;
    unsigned int r = x.u + 0x7FFF + ((x.u >> 16) & 1);   // RNE; finite inputs
    return (unsigned short)(r >> 16);
}

// fp32 -> bf16 cast, 4 elems/thread
__global__ __launch_bounds__(256) void cast_f32_bf16(const float* __restrict__ s,
                                                     unsigned short* __restrict__ d, int n4) {
    int i = blockIdx.x * 256 + threadIdx.x;
    if (i < n4) {
        float4 v = ((const float4*)s)[i];
        ushort4 o;
        o.x = f2bf(v.x); o.y = f2bf(v.y); o.z = f2bf(v.z); o.w = f2bf(v.w);
        ((ushort4*)d)[i] = o;
    }
}

__device__ inline void storeC(float* p, float v) { *p = v; }
__device__ inline void storeC(unsigned short* p, float v) { *p = f2bf(v); }

// async 16B global->LDS; within a wave LDS dest must be base + lane*16
#define GLL16(gp, lp) __builtin_amdgcn_global_load_lds( \
    (const __attribute__((address_space(1))) unsigned int*)(gp), \
    (__attribute__((address_space(3))) unsigned int*)(lp), 16, 0, 0)

// C[m][n] = sum_k A[m][k]*B[n][k]; A: MxK bf16 row-major, B: NxK bf16 row-major.
// 128x128 tile, BK=32, 4 waves 2x2, wave does 64x64 via 4x4 of 16x16x32 MFMA.
// TRANSOUT: write C transposed as bf16 CT[n][m] (packed 4-row 8B stores).
template <typename OutT, bool TRANSOUT = false>
__global__ __launch_bounds__(256) void gemm_nt_mfma(const unsigned short* __restrict__ A,
                                                    const unsigned short* __restrict__ B,
                                                    OutT* __restrict__ C,
                                                    int M, int N, int K) {
    __shared__ unsigned short As[128 * 32];
    __shared__ unsigned short Bs[128 * 32];
    const int tid = threadIdx.x;
    const int lane = tid & 63;
    const int w = tid >> 6;
    const int m0 = blockIdx.y * 128, n0 = blockIdx.x * 128;
    const int wr = (w >> 1) * 64, wc = (w & 1) * 64;
    const int srow = tid >> 2;
    const int scol = (tid & 3) * 8;
    const int quad = lane >> 4, l16 = lane & 15;

    floatx4 acc[4][4] = {};

    for (int k0 = 0; k0 < K; k0 += 32) {
        __syncthreads();
        const unsigned short* gA = A + (size_t)(m0 + srow) * K + k0 + scol;
        const unsigned short* gB = B + (size_t)(n0 + srow) * K + k0 + scol;
        GLL16(gA,                  As + srow * 32 + scol);
        GLL16(gA + (size_t)64 * K, As + (64 + srow) * 32 + scol);
        GLL16(gB,                  Bs + srow * 32 + scol);
        GLL16(gB + (size_t)64 * K, Bs + (64 + srow) * 32 + scol);
        __syncthreads();

        bf16x8 af[4], bg[4];
        #pragma unroll
        for (int i = 0; i < 4; ++i)
            af[i] = *(const bf16x8*)(As + (wr + i * 16 + l16) * 32 + quad * 8);
        #pragma unroll
        for (int j = 0; j < 4; ++j)
            bg[j] = *(const bf16x8*)(Bs + (wc + j * 16 + l16) * 32 + quad * 8);
        #pragma unroll
        for (int i = 0; i < 4; ++i)
            #pragma unroll
            for (int j = 0; j < 4; ++j)
                acc[i][j] = __builtin_amdgcn_mfma_f32_16x16x32_bf16(af[i], bg[j], acc[i][j], 0, 0, 0);
    }

    // C/D layout: col = lane&15, row = quad*4 + reg
    #pragma unroll
    for (int i = 0; i < 4; ++i) {
        #pragma unroll
        for (int j = 0; j < 4; ++j) {
            int col = n0 + wc + j * 16 + l16;
            int rowb = m0 + wr + i * 16 + quad * 4;
            if constexpr (TRANSOUT) {
                ushort4 pk;
                pk.x = f2bf(acc[i][j][0]);
                pk.y = f2bf(acc[i][j][1]);
                pk.z = f2bf(acc[i][j][2]);
                pk.w = f2bf(acc[i][j][3]);
                *(ushort4*)&C[(size_t)col * M + rowb] = pk;
            } else {
                #pragma unroll
                for (int r = 0; r < 4; ++r)
                    storeC(&C[(size_t)(rowb + r) * N + col], acc[i][j][r]);
            }
        }
    }
}

// In-place RoPE on bf16 [SEQ][nh*HDIM]; cos/sin fp32, cos[s][d]==cos[s][d+64].
__global__ __launch_bounds__(256) void rope_bf16(unsigned short* __restrict__ x,
                                                 const float* __restrict__ cosb,
                                                 const float* __restrict__ sinb,
                                                 int nh) {
    int idx = blockIdx.x * 256 + threadIdx.x;
    int d = idx & 63;
    int t = idx >> 6;
    int h = t % nh;
    int s = t / nh;
    float cs = cosb[s * HDIM + d];
    float sn = sinb[s * HDIM + d];
    unsigned short* p = x + (size_t)s * nh * HDIM + h * HDIM + d;
    float x1 = bf2f(p[0]), x2 = bf2f(p[64]);
    p[0]  = f2bf(x1 * cs - x2 * sn);
    p[64] = f2bf(x2 * cs + x1 * sn);
}

// MFMA flash attention. grid (NQT, NHEAD), block 256 (4 waves).
// Block: head h, q-rows s0..s0+63; wave w owns q-rows s0+16w .. +16.
// q: bf16 [SEQ][NHEAD*HDIM] (roped); k: bf16 [SEQ][NKVH*HDIM] (roped);
// vt: bf16 [NKVH*HDIM][SEQ] (V transposed); ao: bf16 [SEQ][NHEAD*HDIM].
__global__ __launch_bounds__(256) void attn_mfma(const unsigned short* __restrict__ qg,
                                                 const unsigned short* __restrict__ kgb,
                                                 const unsigned short* __restrict__ vtg,
                                                 unsigned short* __restrict__ ao) {
    __shared__ unsigned short Ks[64 * 128];   // [key][dim], chunk-swizzled
    __shared__ unsigned short Vs[128 * 64];   // [dim][key], chunk-swizzled
    __shared__ unsigned short Ps[4][16 * 64]; // wave-private P, chunk-swizzled
    const int h = blockIdx.y;
    const int qt = (NQT - 1) - blockIdx.x;    // long (high-qt) blocks dispatch first
    const int s0 = qt * 64;
    const int kvh = h >> 2;                   // NHEAD/NKVH = 4
    const int tid = threadIdx.x;
    const int w = tid >> 6, lane = tid & 63;
    const int quad = lane >> 4, l16 = lane & 15;

    // Q fragments straight from global (invariant over k-tiles)
    bf16x8 aq[4];
    {
        const unsigned short* qrowp = qg + (size_t)(s0 + w * 16 + l16) * (NHEAD * HDIM) + h * HDIM;
        #pragma unroll
        for (int ks = 0; ks < 4; ++ks)
            aq[ks] = *(const bf16x8*)(qrowp + ks * 32 + quad * 8);
    }

    floatx4 acc_o[8] = {};
    float m_r[4], l_r[4];
    #pragma unroll
    for (int r = 0; r < 4; ++r) { m_r[r] = -1e30f; l_r[r] = 0.f; }

    const int srow16 = tid >> 4, sc16 = tid & 15;   // K staging: 16 rows x 16 chunks / call
    const int sdim8 = tid >> 3, skc8 = tid & 7;     // V staging: 32 dims x 8 chunks / call

    for (int t = 0; t <= qt; ++t) {
        __syncthreads();   // prior tile's LDS reads complete
        #pragma unroll
        for (int rl = 0; rl < 4; ++rl) {
            int key = rl * 16 + srow16;
            int cg = sc16 ^ (key & 7);   // swizzle on global side
            const unsigned short* gp = kgb + (size_t)(t * 64 + key) * (NKVH * HDIM) + kvh * HDIM + cg * 8;
            GLL16(gp, Ks + key * 128 + sc16 * 8);
        }
        #pragma unroll
        for (int rl = 0; rl < 4; ++rl) {
            int dim = rl * 32 + sdim8;
            int kg2 = skc8 ^ (dim & 7);
            const unsigned short* gp = vtg + (size_t)(kvh * HDIM + dim) * SEQ + t * 64 + kg2 * 8;
            GLL16(gp, Vs + dim * 64 + skc8 * 8);
        }
        __syncthreads();   // drains vmcnt -> tiles valid

        // S = Q K^T  (16 MFMAs)
        floatx4 acc_s[4] = {};
        #pragma unroll
        for (int ks = 0; ks < 4; ++ks)
            #pragma unroll
            for (int jt = 0; jt < 4; ++jt) {
                bf16x8 bk = *(const bf16x8*)(Ks + (jt * 16 + l16) * 128 +
                                             (((ks * 4 + quad) ^ (l16 & 7)) * 8));
                acc_s[jt] = __builtin_amdgcn_mfma_f32_16x16x32_bf16(aq[ks], bk, acc_s[jt], 0, 0, 0);
            }

        float s_v[4][4];
        #pragma unroll
        for (int jt = 0; jt < 4; ++jt)
            #pragma unroll
            for (int r = 0; r < 4; ++r)
                s_v[jt][r] = acc_s[jt][r] * SCALE;
        if (t == qt) {   // diagonal tile: causal mask (block-uniform branch)
            #pragma unroll
            for (int jt = 0; jt < 4; ++jt) {
                int key = t * 64 + jt * 16 + l16;
                #pragma unroll
                for (int r = 0; r < 4; ++r) {
                    int qrow = s0 + w * 16 + quad * 4 + r;
                    if (key > qrow) s_v[jt][r] = -1e30f;
                }
            }
        }

        // online softmax; row r lives in lanes sharing quad, spread over l16
        float p_v[4][4];
        #pragma unroll
        for (int r = 0; r < 4; ++r) {
            float v = fmaxf(fmaxf(s_v[0][r], s_v[1][r]), fmaxf(s_v[2][r], s_v[3][r]));
            #pragma unroll
            for (int off = 1; off < 16; off <<= 1) v = fmaxf(v, __shfl_xor(v, off));
            float mn = fmaxf(m_r[r], v);
            float alpha = __expf(m_r[r] - mn);
            m_r[r] = mn;
            float sum = 0.f;
            #pragma unroll
            for (int jt = 0; jt < 4; ++jt) { p_v[jt][r] = __expf(s_v[jt][r] - mn); sum += p_v[jt][r]; }
            #pragma unroll
            for (int off = 1; off < 16; off <<= 1) sum += __shfl_xor(sum, off);
            l_r[r] = l_r[r] * alpha + sum;
            #pragma unroll
            for (int nt = 0; nt < 8; ++nt) acc_o[nt][r] *= alpha;
        }

        // P (C-layout) -> wave-private LDS in A-layout-readable, swizzled form
        unsigned short* pw = Ps[w];
        #pragma unroll
        for (int jt = 0; jt < 4; ++jt)
            #pragma unroll
            for (int r = 0; r < 4; ++r) {
                int row = quad * 4 + r;
                int c = (2 * jt + (l16 >> 3)) ^ (row & 7);
                pw[row * 64 + c * 8 + (l16 & 7)] = f2bf(p_v[jt][r]);
            }
        // O += P V  (16 MFMAs); wave-private P needs no barrier (lgkmcnt only)
        #pragma unroll
        for (int ks = 0; ks < 2; ++ks) {
            bf16x8 ap = *(const bf16x8*)(pw + l16 * 64 + (((ks * 4 + quad) ^ (l16 & 7)) * 8));
            #pragma unroll
            for (int nt = 0; nt < 8; ++nt) {
                bf16x8 bv = *(const bf16x8*)(Vs + (nt * 16 + l16) * 64 +
                                             (((ks * 4 + quad) ^ (l16 & 7)) * 8));
                acc_o[nt] = __builtin_amdgcn_mfma_f32_16x16x32_bf16(ap, bv, acc_o[nt], 0, 0, 0);
            }
        }
    }

    #pragma unroll
    for (int r = 0; r < 4; ++r) {
        float inv = 1.f / l_r[r];
        int qrow = s0 + w * 16 + quad * 4 + r;
        unsigned short* op = ao + (size_t)qrow * (NHEAD * HDIM) + h * HDIM + l16;
        #pragma unroll
        for (int nt = 0; nt < 8; ++nt)
            op[nt * 16] = f2bf(acc_o[nt][r] * inv);
    }
}

extern "C" void kernel_launch(void* const* d_in, const int* in_sizes, int n_in,
                              void* d_out, int out_size, void* d_ws, size_t ws_size,
                              hipStream_t stream) {
    const float* hidden = (const float*)d_in[0];
    const float* cosb   = (const float*)d_in[1];
    const float* sinb   = (const float*)d_in[2];
    const float* wq     = (const float*)d_in[3];
    const float* wk     = (const float*)d_in[4];
    const float* wv     = (const float*)d_in[5];
    const float* wo     = (const float*)d_in[6];
    // d_in[7..9]: k_cache/v_cache/block_ids — scatter+gather by same ids == identity; unused.

    unsigned short* hb  = (unsigned short*)d_ws;             // hidden bf16; reused as attn out
    unsigned short* wb  = hb + (size_t)SEQ * HIDDEN;         // current weight bf16
    unsigned short* qb  = wb + (size_t)HIDDEN * HIDDEN;      // q bf16 [SEQ][4096]
    unsigned short* kb  = qb + (size_t)SEQ * NHEAD * HDIM;   // k bf16 [SEQ][1024]
    unsigned short* vtb = kb + (size_t)SEQ * NKVH * HDIM;    // v^T bf16 [1024][SEQ]
    unsigned short* ao  = hb;

    dim3 blk(256);
    cast_f32_bf16<<<dim3(SEQ * HIDDEN / 1024), blk, 0, stream>>>(hidden, hb, SEQ * HIDDEN / 4);

    // Q projection
    cast_f32_bf16<<<dim3(HIDDEN * HIDDEN / 1024), blk, 0, stream>>>(wq, wb, HIDDEN * HIDDEN / 4);
    gemm_nt_mfma<unsigned short><<<dim3((NHEAD * HDIM) / 128, SEQ / 128), blk, 0, stream>>>(
        hb, wb, qb, SEQ, NHEAD * HDIM, HIDDEN);
    // K projection
    cast_f32_bf16<<<dim3(NKVH * HDIM * HIDDEN / 1024), blk, 0, stream>>>(wk, wb, NKVH * HDIM * HIDDEN / 4);
    gemm_nt_mfma<unsigned short><<<dim3((NKVH * HDIM) / 128, SEQ / 128), blk, 0, stream>>>(
        hb, wb, kb, SEQ, NKVH * HDIM, HIDDEN);
    // V projection -> transposed output vtb[dim][seq]
    cast_f32_bf16<<<dim3(NKVH * HDIM * HIDDEN / 1024), blk, 0, stream>>>(wv, wb, NKVH * HDIM * HIDDEN / 4);
    gemm_nt_mfma<unsigned short, true><<<dim3((NKVH * HDIM) / 128, SEQ / 128), blk, 0, stream>>>(
        hb, wb, vtb, SEQ, NKVH * HDIM, HIDDEN);

    // RoPE on q and k
    rope_bf16<<<dim3(SEQ * NHEAD * 64 / 256), blk, 0, stream>>>(qb, cosb, sinb, NHEAD);
    rope_bf16<<<dim3(SEQ * NKVH * 64 / 256), blk, 0, stream>>>(kb, cosb, sinb, NKVH);

    // MFMA flash attention
    attn_mfma<<<dim3(NQT, NHEAD), blk, 0, stream>>>(qb, kb, vtb, ao);

    // output projection (fp32 out)
    cast_f32_bf16<<<dim3(HIDDEN * HIDDEN / 1024), blk, 0, stream>>>(wo, wb, HIDDEN * HIDDEN / 4);
    gemm_nt_mfma<float><<<dim3(HIDDEN / 128, SEQ / 128), blk, 0, stream>>>(
        ao, wb, (float*)d_out, SEQ, HIDDEN, NHEAD * HDIM);
}